// Round 6
// baseline (87.610 us; speedup 1.0000x reference)
//
#include <hip/hip_runtime.h>
#include <math.h>

// Problem constants
#define NA   12            // atoms per residue
#define NL   256           // residues
#define NN   3072          // NL*NA atoms per batch
#define NB   2             // batches
#define ED   32            // embedding dim
#define KNB  30            // neighbours
#define BIGD 1000000.0f

// Flat output offsets (all stored as float32; int outputs stored as float values)
#define OFF_COORDS 0                       // 2*3072*3   = 18432
#define OFF_MASK   18432                   // 2*3072     = 6144
#define OFF_ENC    24576                   // 2*3072*32  = 196608
#define OFF_DIST   221184                  // 2*3072*30  = 184320
#define OFF_IDX    405504                  // 2*3072*30  = 184320

// key packing: top 20 bits = float bits of SQUARED dist (positive -> uint order
// == float order; sqrt is monotone so d^2-selection == d-selection), low 12
// bits = atom index (0..3071). min(key) == lexicographic (dist, idx) min with
// smallest-index tie-break == jax top_k semantics.
#define KEYVAL 0xFFFFF000u
#define KEYIDX 0x00000FFFu
#define MASKED_D2 1e12f    // sqrt -> ~1e6 == BIGD (trunc err ~14 abs, way under threshold)

static __device__ __forceinline__ unsigned umin32(unsigned a, unsigned b) {
    return a < b ? a : b;
}

#define DPP_MIN_STEP(CTRL)                                                        \
    {                                                                             \
        int t_ = __builtin_amdgcn_update_dpp(v_, v_, (CTRL), 0xf, 0xf, false);    \
        v_ = (int)umin32((unsigned)v_, (unsigned)t_);                             \
    }

#define TREE8(A0,A1,A2,A3,A4,A5,A6,A7) \
    umin32(umin32(umin32((A0),(A1)), umin32((A2),(A3))), \
           umin32(umin32((A4),(A5)), umin32((A6),(A7))))

#define REMOVE_RESCAN(G)                                                          \
    {                                                                             \
        _Pragma("unroll")                                                         \
        for (int u = 0; u < 8; ++u) {                                             \
            const int t = (G) * 8 + u;                                            \
            k[t] = (k[t] == wkey) ? 0xFFFFFFFFu : k[t];                           \
        }                                                                         \
        gm[(G)] = TREE8(k[(G)*8+0],k[(G)*8+1],k[(G)*8+2],k[(G)*8+3],              \
                        k[(G)*8+4],k[(G)*8+5],k[(G)*8+6],k[(G)*8+7]);             \
    }

// ---------------------------------------------------------------------------
// Single fused kernel. 768 blocks x 512 threads (8 waves).
// Blocks 0..383 -> batch 0 rows, 384..767 -> batch 1 rows; block handles rows
// rblk*8 .. rblk*8+7 of its batch (one wave per row).
// Phase 1: cooperatively stage all 3072 {x,y,z,mask} float4 into 48 KB LDS.
// Phase 2: per-wave top-30 from LDS (round-5 extraction, unchanged).
// Phase 3: prep tail (enc graph-norm, coords reshape, mask expand) on the
//          same threads -- independent work, hides under topk latency.
// ---------------------------------------------------------------------------
__global__ __launch_bounds__(512, 4) void fused_kernel(const float* __restrict__ coords,
                                                       const int* __restrict__ mask,
                                                       const float* __restrict__ emb,
                                                       const float* __restrict__ scale,
                                                       const float* __restrict__ shift,
                                                       float* __restrict__ out) {
    __shared__ float4 sc4[NN];        // 48 KB

    int tid  = threadIdx.x;
    int lane = tid & 63;
    int wave = tid >> 6;              // 0..7
    int b    = (int)(blockIdx.x) / 384;
    int rblk = (int)(blockIdx.x) - b * 384;
    const float* cb = coords + (size_t)b * NN * 3;
    const int*   mb = mask + b * NL;

    // ---- Phase 1: stage packed coords+mask into LDS (6 elements/thread) ----
#pragma unroll
    for (int s = 0; s < 6; ++s) {
        int e = tid + s * 512;
        int r = (e * 43691) >> 19;    // e / 12 (magic, exact for e < 4096)
        float4 p;
        p.x = cb[e * 3 + 0];
        p.y = cb[e * 3 + 1];
        p.z = cb[e * 3 + 2];
        p.w = (float)mb[r];
        sc4[e] = p;
    }
    __syncthreads();

    // ---- Phase 2: per-wave top-30 ----
    int i   = rblk * 8 + wave;        // row within batch, 0..3071
    int row = b * NN + i;             // global row
    float4 q = sc4[i];                // uniform address -> LDS broadcast

    if (q.w != 0.f) {
        unsigned k[48];
        unsigned gm[6];

#pragma unroll
        for (int t = 0; t < 48; ++t) {
            int j = t * 64 + lane;
            float4 v = sc4[j];
            float dx = v.x - q.x, dy = v.y - q.y, dz = v.z - q.z;
            float s = dx * dx + dy * dy + dz * dz + 1e-6f;   // squared dist
            s = (v.w != 0.f) ? s : MASKED_D2;
            k[t] = (__float_as_uint(s) & KEYVAL) | (unsigned)j;
        }
#pragma unroll
        for (int g = 0; g < 6; ++g)
            gm[g] = TREE8(k[g*8+0],k[g*8+1],k[g*8+2],k[g*8+3],
                          k[g*8+4],k[g*8+5],k[g*8+6],k[g*8+7]);

        unsigned cur = umin32(umin32(umin32(gm[0], gm[1]), umin32(gm[2], gm[3])),
                              umin32(gm[4], gm[5]));
        unsigned rkey = 0u;

        for (int it = 0; it < KNB; ++it) {
            // 4-step DPP min ladder -> row16 minima; readlane + scalar mins.
            int v_ = (int)cur;
            DPP_MIN_STEP(0xB1)   // quad_perm [1,0,3,2]  (xor 1)
            DPP_MIN_STEP(0x4E)   // quad_perm [2,3,0,1]  (xor 2)
            DPP_MIN_STEP(0x141)  // row_half_mirror      (octet min)
            DPP_MIN_STEP(0x140)  // row_mirror           (row16 min)
            unsigned r0  = (unsigned)__builtin_amdgcn_readlane(v_, 0);
            unsigned r16 = (unsigned)__builtin_amdgcn_readlane(v_, 16);
            unsigned r32 = (unsigned)__builtin_amdgcn_readlane(v_, 32);
            unsigned r48 = (unsigned)__builtin_amdgcn_readlane(v_, 48);
            unsigned wkey = umin32(umin32(r0, r16), umin32(r32, r48));   // SGPR
            rkey = (lane == it) ? wkey : rkey;

            int wg = (int)((wkey & KEYIDX) >> 9);  // j>>6 = slot, slot>>3 = group
            switch (wg) {                           // scalar branch
                case 0: REMOVE_RESCAN(0); break;
                case 1: REMOVE_RESCAN(1); break;
                case 2: REMOVE_RESCAN(2); break;
                case 3: REMOVE_RESCAN(3); break;
                case 4: REMOVE_RESCAN(4); break;
                default: REMOVE_RESCAN(5); break;
            }
            cur = umin32(umin32(umin32(gm[0], gm[1]), umin32(gm[2], gm[3])),
                         umin32(gm[4], gm[5]));
        }

        if (lane < KNB) {
            float d2 = __uint_as_float(rkey & KEYVAL);
            out[OFF_DIST + (size_t)row * KNB + lane] = sqrtf(d2);
            out[OFF_IDX  + (size_t)row * KNB + lane] = (float)(rkey & KEYIDX);
        }
    } else {
        if (lane < KNB) {
            out[OFF_DIST + (size_t)row * KNB + lane] = BIGD;
            out[OFF_IDX  + (size_t)row * KNB + lane] = 0.f;
        }
    }

    // ---- Phase 3: prep tail (enc + coords reshape + mask expand) ----
    int gidx = (int)blockIdx.x * 512 + tid;        // 0..393215

    if (gidx < NB * NN * ED) {                     // 196608 enc elements
        int bb = (gidx >> 5) >= NN ? 1 : 0;        // batch (wave-uniform)
        // wave-level mask sum for batch bb (int4: 64 lanes x 4 = 256 residues)
        const int4* m4 = (const int4*)(mask + bb * NL);
        int4 mv = m4[lane];
        float S = (float)(mv.x + mv.y + mv.z + mv.w);
#pragma unroll
        for (int m = 1; m < 64; m <<= 1) S += __shfl_xor(S, m);

        int c = gidx & (ED - 1);
        float e[NA];
        float colsum = 0.f;
#pragma unroll
        for (int a = 0; a < NA; ++a) { e[a] = emb[a * ED + c]; colsum += e[a]; }
        float cnt  = fmaxf(12.0f * S, 1.0f);
        float mean = S * colsum / cnt;
        float acc  = 0.f;
#pragma unroll
        for (int a = 0; a < NA; ++a) { float dd = e[a] - mean; acc += dd * dd; }
        float var  = (S * acc + ((float)NN - 12.0f * S) * mean * mean) / cnt;
        float rstd = 1.0f / sqrtf(var + 1e-5f);

        int n  = (gidx >> 5) - bb * NN;            // atom index 0..3071
        int nr = (n * 43691) >> 19;                // n / 12
        int mi = mask[bb * NL + nr];
        float v = 0.f;
        if (mi) {
            float en = emb[(n - nr * NA) * ED + c];
            v = (en - mean) * rstd * scale[c] + shift[c];
        }
        out[OFF_ENC + gidx] = v;
    }

    if (gidx < NB * NN * 3) {                      // 18432: pure reshape copy
        out[OFF_COORDS + gidx] = coords[gidx];
    }

    if (gidx < NB * NN) {                          // 6144: mask expand
        int bb = gidx >= NN ? 1 : 0;
        int nn = gidx - bb * NN;
        int nr = (nn * 43691) >> 19;               // nn / 12
        out[OFF_MASK + gidx] = (float)mask[bb * NL + nr];
    }
}

// ---------------------------------------------------------------------------
extern "C" void kernel_launch(void* const* d_in, const int* in_sizes, int n_in,
                              void* d_out, int out_size, void* d_ws, size_t ws_size,
                              hipStream_t stream) {
    const float* coords = (const float*)d_in[0];   // (2,256,12,3)
    const int*   mask   = (const int*)d_in[1];     // (2,256)
    const float* emb    = (const float*)d_in[2];   // (12,32)
    const float* scale  = (const float*)d_in[3];   // (32)
    const float* shift  = (const float*)d_in[4];   // (32)
    float* out = (float*)d_out;

    fused_kernel<<<NB * (NN / 8), 512, 0, stream>>>(coords, mask, emb, scale, shift, out);
}